// Round 1
// baseline (532.408 us; speedup 1.0000x reference)
//
#include <hip/hip_runtime.h>

// ---------------------------------------------------------------------------
// AttentionBlock: qkv-proj (+LN on q,k) -> masked flash attention -> out-proj
// B=2, S=2048, E=2048, H=16, D=128. All matmuls bf16 MFMA (16x16x32), fp32 acc.
// ---------------------------------------------------------------------------

typedef __attribute__((ext_vector_type(8))) __bf16 bf16x8;
typedef __attribute__((ext_vector_type(4))) float f32x4;
typedef __attribute__((ext_vector_type(8))) unsigned short ushort8;
typedef __attribute__((ext_vector_type(4))) unsigned short ushort4v;
typedef __attribute__((ext_vector_type(4))) float float4v;

#define MFMA16(a, b, c) __builtin_amdgcn_mfma_f32_16x16x32_bf16((a), (b), (c), 0, 0, 0)

__device__ __forceinline__ unsigned short f2bf(float f) {
  unsigned u = __builtin_bit_cast(unsigned, f);
  u += 0x7fffu + ((u >> 16) & 1u);           // RNE
  return (unsigned short)(u >> 16);
}

__device__ __forceinline__ void gload_lds16(const void* g, void* l) {
  __builtin_amdgcn_global_load_lds(
      (const __attribute__((address_space(1))) void*)g,
      (__attribute__((address_space(3))) void*)l, 16, 0, 0);
}

// ---------------- prep: elementwise add + fp32->bf16 -----------------------
__global__ __launch_bounds__(256) void k_cvt(const float4v* __restrict__ x,
                                             const float4v* __restrict__ y,
                                             ushort4v* __restrict__ o, int n4) {
  int i = blockIdx.x * 256 + threadIdx.x;
  if (i >= n4) return;
  float4v a = x[i];
  if (y) { float4v b = y[i]; a = a + b; }
  ushort4v r;
  r[0] = f2bf(a[0]); r[1] = f2bf(a[1]); r[2] = f2bf(a[2]); r[3] = f2bf(a[3]);
  o[i] = r;
}

// ---------------- prep: weight transpose fp32[K][N] -> bf16[N][K] ----------
__global__ __launch_bounds__(256) void k_tr(const float* __restrict__ s0, const float* __restrict__ s1,
                                            const float* __restrict__ s2, const float* __restrict__ s3,
                                            unsigned short* __restrict__ d0, unsigned short* __restrict__ d1,
                                            unsigned short* __restrict__ d2, unsigned short* __restrict__ d3) {
  __shared__ float t[32][33];
  const float* S; unsigned short* D;
  switch (blockIdx.z) {
    case 0: S = s0; D = d0; break;
    case 1: S = s1; D = d1; break;
    case 2: S = s2; D = d2; break;
    default: S = s3; D = d3; break;
  }
  int x = threadIdx.x & 31, y = threadIdx.x >> 5;
  int r0 = blockIdx.y * 32, c0 = blockIdx.x * 32;
#pragma unroll
  for (int i = 0; i < 4; ++i) t[y + 8 * i][x] = S[(size_t)(r0 + y + 8 * i) * 2048 + c0 + x];
  __syncthreads();
#pragma unroll
  for (int i = 0; i < 4; ++i)
    D[(size_t)(c0 + y + 8 * i) * 2048 + r0 + x] = f2bf(t[x][y + 8 * i]);
}

// ---------------- prep: mask int32 -> bitmask (1 bit/key) ------------------
__global__ __launch_bounds__(256) void k_mask(const int* __restrict__ m,
                                              unsigned long long* __restrict__ out) {
  int i = blockIdx.x * 256 + threadIdx.x;
  unsigned long long b = __ballot(m[i] != 0);
  if ((threadIdx.x & 63) == 0) out[i >> 6] = b;
}

// ---------------- GEMM 128x128 tile, BK=64, 4 waves (m97 structure) --------
// A[4096][2048] bf16 row-major, Bt[2048][2048] bf16 = B^T row-major.
// MODE 0: plain bf16 -> [B,H,S,D];  1: LN*scale*rsqrt(D) (Q);  2: LN*scale (K);
// MODE 3: fp32 direct to [4096][2048] (final out-proj).
template <int MODE>
__global__ __launch_bounds__(256) void k_gemm(const unsigned short* __restrict__ A,
                                              const unsigned short* __restrict__ Bt,
                                              void* __restrict__ Cv,
                                              const float* __restrict__ lnsc) {
  constexpr int K = 2048;
  __shared__ __attribute__((aligned(16))) unsigned short sA[128 * 64];
  __shared__ __attribute__((aligned(16))) unsigned short sB[128 * 64];
  __shared__ float sSum[2][128];
  __shared__ float sSq[2][128];
  int tid = threadIdx.x;
  int lane = tid & 63, w = tid >> 6;
  int wr = w >> 1, wc = w & 1;
  int r15 = lane & 15, blk = lane >> 4;
  int n0 = blockIdx.x * 128, m0 = blockIdx.y * 128;
  const unsigned short* Abase = A + (size_t)m0 * K;
  const unsigned short* Bbase = Bt + (size_t)n0 * K;
  f32x4 acc[4][4] = {};

  for (int kt = 0; kt < K; kt += 64) {
#pragma unroll
    for (int i = 0; i < 4; ++i) {   // stage A tile: 1024 16B chunks, XOR-swizzled source
      int c = i * 256 + tid;
      int row = c >> 3, cc = c & 7;
      gload_lds16(Abase + (size_t)row * K + kt + ((cc ^ (row & 7)) * 8), &sA[c * 8]);
    }
#pragma unroll
    for (int i = 0; i < 4; ++i) {   // stage B tile
      int c = i * 256 + tid;
      int row = c >> 3, cc = c & 7;
      gload_lds16(Bbase + (size_t)row * K + kt + ((cc ^ (row & 7)) * 8), &sB[c * 8]);
    }
    __syncthreads();
#pragma unroll
    for (int kk = 0; kk < 2; ++kk) {
      bf16x8 av[4], bv[4];
#pragma unroll
      for (int i = 0; i < 4; ++i) {
        int row = wr * 64 + i * 16 + r15;
        av[i] = *(const bf16x8*)&sA[row * 64 + (((kk * 4 + blk) ^ (row & 7)) * 8)];
      }
#pragma unroll
      for (int j = 0; j < 4; ++j) {
        int row = wc * 64 + j * 16 + r15;
        bv[j] = *(const bf16x8*)&sB[row * 64 + (((kk * 4 + blk) ^ (row & 7)) * 8)];
      }
#pragma unroll
      for (int i = 0; i < 4; ++i)
#pragma unroll
        for (int j = 0; j < 4; ++j) acc[i][j] = MFMA16(av[i], bv[j], acc[i][j]);
    }
    __syncthreads();
  }

  if constexpr (MODE == 3) {
    float* C = (float*)Cv;
#pragma unroll
    for (int i = 0; i < 4; ++i)
#pragma unroll
      for (int r = 0; r < 4; ++r)
#pragma unroll
        for (int j = 0; j < 4; ++j) {
          int rowl = wr * 64 + i * 16 + blk * 4 + r;   // C layout: row=(lane>>4)*4+reg
          int coll = wc * 64 + j * 16 + r15;           //           col=lane&15
          C[(size_t)(m0 + rowl) * 2048 + n0 + coll] = acc[i][j][r];
        }
    return;
  } else {
    if constexpr (MODE == 1 || MODE == 2) {
      // per-row stats over the 128 cols (= head_dim) of this tile
#pragma unroll
      for (int i = 0; i < 4; ++i)
#pragma unroll
        for (int r = 0; r < 4; ++r) {
          float sm = 0.f, sq = 0.f;
#pragma unroll
          for (int j = 0; j < 4; ++j) { float v = acc[i][j][r]; sm += v; sq += v * v; }
          sm += __shfl_xor(sm, 1); sq += __shfl_xor(sq, 1);
          sm += __shfl_xor(sm, 2); sq += __shfl_xor(sq, 2);
          sm += __shfl_xor(sm, 4); sq += __shfl_xor(sq, 4);
          sm += __shfl_xor(sm, 8); sq += __shfl_xor(sq, 8);
          if (r15 == 0) {
            int rowl = wr * 64 + i * 16 + blk * 4 + r;
            sSum[wc][rowl] = sm; sSq[wc][rowl] = sq;
          }
        }
      __syncthreads();
    }
    unsigned short* Hout = (unsigned short*)Cv;
    int h = blockIdx.x;  // BN=128 == D: one head per n-block
#pragma unroll
    for (int i = 0; i < 4; ++i)
#pragma unroll
      for (int r = 0; r < 4; ++r) {
        int rowl = wr * 64 + i * 16 + blk * 4 + r;
        float mean = 0.f, rstd = 1.f;
        if constexpr (MODE == 1 || MODE == 2) {
          float sm = sSum[0][rowl] + sSum[1][rowl];
          float sq = sSq[0][rowl] + sSq[1][rowl];
          mean = sm * 0.0078125f;
          float var = sq * 0.0078125f - mean * mean;
          rstd = rsqrtf(var + 1e-6f);
        }
        int rowg = m0 + rowl;
        int b = rowg >> 11, s = rowg & 2047;
        unsigned short* orow = Hout + (((size_t)b * 16 + h) * 2048 + s) * 128;
#pragma unroll
        for (int j = 0; j < 4; ++j) {
          int d = wc * 64 + j * 16 + r15;
          float v = acc[i][j][r];
          if constexpr (MODE == 1) v = (v - mean) * rstd * lnsc[d] * 0.08838834764831845f;
          if constexpr (MODE == 2) v = (v - mean) * rstd * lnsc[d];
          orow[d] = f2bf(v);
        }
      }
  }
}

// ---------------- flash attention, swapped QK^T, 4 waves x 16 q-rows -------
__global__ __launch_bounds__(256) void k_attn(const unsigned short* __restrict__ Qh,
                                              const unsigned short* __restrict__ Kh,
                                              const unsigned short* __restrict__ Vh,
                                              const unsigned* __restrict__ maskb,
                                              unsigned short* __restrict__ O) {
  __shared__ __attribute__((aligned(16))) unsigned short sK[32 * 128];  // swizzled
  __shared__ __attribute__((aligned(16))) unsigned short sVt[128 * 36]; // V^T, padded
  __shared__ float sO[64 * 132];
  int tid = threadIdx.x, lane = tid & 63, w = tid >> 6;
  int r15 = lane & 15, blk = lane >> 4;
  int bh = blockIdx.y, b = bh >> 4, h = bh & 15;
  int qb = blockIdx.x * 64;
  size_t base = (size_t)bh * (2048 * 128);
  int qrow = qb + w * 16 + r15;

  bf16x8 qf[4];  // Q rows hoisted to registers (B-operand fragments)
  {
    const unsigned short* qp = Qh + base + (size_t)qrow * 128 + blk * 8;
#pragma unroll
    for (int kk = 0; kk < 4; ++kk) qf[kk] = *(const bf16x8*)(qp + kk * 32);
  }
  const unsigned* mrow = maskb + ((size_t)b * 2048 + qrow) * 64;

  f32x4 o[8] = {};
  float m = -1e30f, lsum = 0.f;

  for (int kc = 0; kc < 2048; kc += 32) {
#pragma unroll
    for (int i = 0; i < 2; ++i) {   // stage K chunk [32][128], swizzled source
      int c = i * 256 + tid;
      int row = c >> 4, cc = c & 15;
      gload_lds16(Kh + base + (size_t)(kc + row) * 128 + ((cc ^ (row & 7)) * 8), &sK[c * 8]);
    }
    {   // stage V^T [d][key]
      int key = tid >> 3, d0 = (tid & 7) * 16;
      const unsigned short* vp = Vh + base + (size_t)(kc + key) * 128 + d0;
      ushort8 v0 = *(const ushort8*)vp;
      ushort8 v1 = *(const ushort8*)(vp + 8);
#pragma unroll
      for (int e = 0; e < 8; ++e) {
        sVt[(d0 + e) * 36 + key] = v0[e];
        sVt[(d0 + 8 + e) * 36 + key] = v1[e];
      }
    }
    __syncthreads();

    // S^T = K . Q^T  (keys as M so softmax axis is lane-local-ish)
    f32x4 st0 = {0.f, 0.f, 0.f, 0.f}, st1 = {0.f, 0.f, 0.f, 0.f};
#pragma unroll
    for (int kk = 0; kk < 4; ++kk) {
      int cc = (4 * kk + blk) ^ (r15 & 7);
      bf16x8 k0 = *(const bf16x8*)&sK[r15 * 128 + cc * 8];
      bf16x8 k1 = *(const bf16x8*)&sK[(16 + r15) * 128 + cc * 8];
      st0 = MFMA16(k0, qf[kk], st0);
      st1 = MFMA16(k1, qf[kk], st1);
    }
    // mask + online softmax. lane holds q=lane&15, keys = s*16 + blk*4 + r
    unsigned mw = mrow[kc >> 5];
    float pvv[8];
    float cmax = -1e30f;
#pragma unroll
    for (int t = 0; t < 8; ++t) {
      int s = t >> 2, r = t & 3;
      int ks = s * 16 + blk * 4 + r;
      float sv = s ? st1[r] : st0[r];
      sv = ((mw >> ks) & 1u) ? sv : -1e30f;
      pvv[t] = sv;
      cmax = fmaxf(cmax, sv);
    }
    cmax = fmaxf(cmax, __shfl_xor(cmax, 16));
    cmax = fmaxf(cmax, __shfl_xor(cmax, 32));
    float mnew = fmaxf(m, cmax);
    float fac = __expf(m - mnew);
    float csum = 0.f;
#pragma unroll
    for (int t = 0; t < 8; ++t) { pvv[t] = __expf(pvv[t] - mnew); csum += pvv[t]; }
    csum += __shfl_xor(csum, 16);
    csum += __shfl_xor(csum, 32);
    lsum = lsum * fac + csum;
    m = mnew;

    ushort8 pu;
#pragma unroll
    for (int t = 0; t < 8; ++t) pu[t] = f2bf(pvv[t]);
    bf16x8 pf = __builtin_bit_cast(bf16x8, pu);

    // rescale O (O rows are q = blk*4+r; fac lives at lane q)
    float fr[4];
#pragma unroll
    for (int r = 0; r < 4; ++r) fr[r] = __shfl(fac, blk * 4 + r);
#pragma unroll
    for (int t8 = 0; t8 < 8; ++t8) {
      o[t8][0] *= fr[0]; o[t8][1] *= fr[1]; o[t8][2] *= fr[2]; o[t8][3] *= fr[3];
    }
    // PV: V fragment k-map must match P's forced map: key(blk,j)=16*(j>>2)+4*blk+(j&3)
#pragma unroll
    for (int t8 = 0; t8 < 8; ++t8) {
      const unsigned short* vb = &sVt[(t8 * 16 + r15) * 36 + blk * 4];
      ushort4v x0 = *(const ushort4v*)vb;
      ushort4v x1 = *(const ushort4v*)(vb + 16);
      ushort8 u;
      u[0] = x0[0]; u[1] = x0[1]; u[2] = x0[2]; u[3] = x0[3];
      u[4] = x1[0]; u[5] = x1[1]; u[6] = x1[2]; u[7] = x1[3];
      o[t8] = MFMA16(pf, __builtin_bit_cast(bf16x8, u), o[t8]);
    }
    __syncthreads();
  }

  float inv = 1.f / lsum;
  float ir[4];
#pragma unroll
  for (int r = 0; r < 4; ++r) ir[r] = __shfl(inv, blk * 4 + r);
#pragma unroll
  for (int t8 = 0; t8 < 8; ++t8)
#pragma unroll
    for (int r = 0; r < 4; ++r)
      sO[(w * 16 + blk * 4 + r) * 132 + t8 * 16 + r15] = o[t8][r] * ir[r];
  __syncthreads();
  {
    int row = tid >> 2, d0 = (tid & 3) * 32;
    unsigned short* op = O + (size_t)(b * 2048 + qb + row) * 2048 + h * 128 + d0;
#pragma unroll
    for (int g = 0; g < 4; ++g) {
      ushort8 pk;
#pragma unroll
      for (int e = 0; e < 8; ++e) pk[e] = f2bf(sO[row * 132 + d0 + g * 8 + e]);
      *(ushort8*)(op + g * 8) = pk;
    }
  }
}

// ---------------------------------------------------------------------------
extern "C" void kernel_launch(void* const* d_in, const int* in_sizes, int n_in,
                              void* d_out, int out_size, void* d_ws, size_t ws_size,
                              hipStream_t stream) {
  const float* q      = (const float*)d_in[0];
  const float* kv     = (const float*)d_in[1];
  const float* q_pos  = (const float*)d_in[2];
  const float* kv_pos = (const float*)d_in[3];
  const int*   mask   = (const int*)d_in[4];
  const float* wq     = (const float*)d_in[5];
  const float* wk     = (const float*)d_in[6];
  const float* wv     = (const float*)d_in[7];
  const float* qls    = (const float*)d_in[8];
  const float* kls    = (const float*)d_in[9];
  const float* wo     = (const float*)d_in[10];

  char* ws = (char*)d_ws;
  const size_t SZ_ACT = (size_t)4096 * 2048 * 2;  // 16 MiB
  const size_t SZ_W   = (size_t)2048 * 2048 * 2;  // 8 MiB
  unsigned short* a_q = (unsigned short*)(ws);
  unsigned short* a_k = (unsigned short*)(ws + SZ_ACT);
  unsigned short* a_v = (unsigned short*)(ws + 2 * SZ_ACT);
  unsigned short* Qh  = (unsigned short*)(ws + 3 * SZ_ACT);
  unsigned short* Kh  = (unsigned short*)(ws + 4 * SZ_ACT);
  unsigned short* Vh  = (unsigned short*)(ws + 5 * SZ_ACT);
  unsigned short* wqt = (unsigned short*)(ws + 6 * SZ_ACT);
  unsigned short* wkt = (unsigned short*)(ws + 6 * SZ_ACT + SZ_W);
  unsigned short* wvt = (unsigned short*)(ws + 6 * SZ_ACT + 2 * SZ_W);
  unsigned short* wot = (unsigned short*)(ws + 6 * SZ_ACT + 3 * SZ_W);
  unsigned*       mkb = (unsigned*)(ws + 6 * SZ_ACT + 4 * SZ_W);
  unsigned short* Ob  = a_q;  // a_q dead after Q-projection; reuse for attn out

  const size_t NEED = 6 * SZ_ACT + 4 * SZ_W + (size_t)2 * 2048 * 64 * 4;
  if (ws_size < NEED) return;  // leave d_out poisoned -> visible failure

  k_cvt<<<8192, 256, 0, stream>>>((const float4v*)q,  (const float4v*)q_pos,  (ushort4v*)a_q, 2097152);
  k_cvt<<<8192, 256, 0, stream>>>((const float4v*)kv, (const float4v*)kv_pos, (ushort4v*)a_k, 2097152);
  k_cvt<<<8192, 256, 0, stream>>>((const float4v*)kv, nullptr,                (ushort4v*)a_v, 2097152);
  k_tr<<<dim3(64, 64, 4), 256, 0, stream>>>(wq, wk, wv, wo, wqt, wkt, wvt, wot);
  k_mask<<<32768, 256, 0, stream>>>(mask, (unsigned long long*)mkb);

  k_gemm<1><<<dim3(16, 32), 256, 0, stream>>>(a_q, wqt, Qh, qls);
  k_gemm<2><<<dim3(16, 32), 256, 0, stream>>>(a_k, wkt, Kh, kls);
  k_gemm<0><<<dim3(16, 32), 256, 0, stream>>>(a_v, wvt, Vh, nullptr);

  k_attn<<<dim3(32, 32), 256, 0, stream>>>(Qh, Kh, Vh, mkb, Ob);

  k_gemm<3><<<dim3(16, 32), 256, 0, stream>>>(Ob, wot, d_out, nullptr);
}

// Round 3
// 373.627 us; speedup vs baseline: 1.4250x; 1.4250x over previous
//
#include <hip/hip_runtime.h>
#include <hip/hip_bf16.h>

// ---------------------------------------------------------------------------
// AttentionBlock: qkv-proj (+LN on q,k) -> masked flash attention -> out-proj
// B=2, S=2048, E=2048, H=16, D=128. All matmuls bf16 MFMA (16x16x32), fp32 acc.
// ---------------------------------------------------------------------------

typedef __attribute__((ext_vector_type(8))) __bf16 bf16x8;
typedef __attribute__((ext_vector_type(4))) float f32x4;
typedef __attribute__((ext_vector_type(8))) unsigned short ushort8;
typedef __attribute__((ext_vector_type(4))) unsigned short ushort4v;
typedef __attribute__((ext_vector_type(4))) float float4v;

#define MFMA16(a, b, c) __builtin_amdgcn_mfma_f32_16x16x32_bf16((a), (b), (c), 0, 0, 0)

__device__ __forceinline__ unsigned short f2bf(float f) {
  unsigned u = __builtin_bit_cast(unsigned, f);
  u += 0x7fffu + ((u >> 16) & 1u);           // RNE
  return (unsigned short)(u >> 16);
}

__device__ __forceinline__ void gload_lds16(const void* g, void* l) {
  __builtin_amdgcn_global_load_lds(
      (const __attribute__((address_space(1))) void*)g,
      (__attribute__((address_space(3))) void*)l, 16, 0, 0);
}

// ---------------- prep: elementwise add + fp32->bf16 -----------------------
__global__ __launch_bounds__(256) void k_cvt(const float4v* __restrict__ x,
                                             const float4v* __restrict__ y,
                                             ushort4v* __restrict__ o, int n4) {
  int i = blockIdx.x * 256 + threadIdx.x;
  if (i >= n4) return;
  float4v a = x[i];
  if (y) { float4v b = y[i]; a = a + b; }
  ushort4v r;
  r[0] = f2bf(a[0]); r[1] = f2bf(a[1]); r[2] = f2bf(a[2]); r[3] = f2bf(a[3]);
  o[i] = r;
}

// ---------------- prep: weight transpose fp32[K][N] -> bf16[N][K] ----------
__global__ __launch_bounds__(256) void k_tr(const float* __restrict__ s0, const float* __restrict__ s1,
                                            const float* __restrict__ s2, const float* __restrict__ s3,
                                            unsigned short* __restrict__ d0, unsigned short* __restrict__ d1,
                                            unsigned short* __restrict__ d2, unsigned short* __restrict__ d3) {
  __shared__ float t[32][33];
  const float* S; unsigned short* D;
  switch (blockIdx.z) {
    case 0: S = s0; D = d0; break;
    case 1: S = s1; D = d1; break;
    case 2: S = s2; D = d2; break;
    default: S = s3; D = d3; break;
  }
  int x = threadIdx.x & 31, y = threadIdx.x >> 5;
  int r0 = blockIdx.y * 32, c0 = blockIdx.x * 32;
#pragma unroll
  for (int i = 0; i < 4; ++i) t[y + 8 * i][x] = S[(size_t)(r0 + y + 8 * i) * 2048 + c0 + x];
  __syncthreads();
#pragma unroll
  for (int i = 0; i < 4; ++i)
    D[(size_t)(c0 + y + 8 * i) * 2048 + r0 + x] = f2bf(t[x][y + 8 * i]);
}

// ---------------- prep: mask int32 -> bitmask (1 bit/key) ------------------
__global__ __launch_bounds__(256) void k_mask(const int* __restrict__ m,
                                              unsigned long long* __restrict__ out) {
  int i = blockIdx.x * 256 + threadIdx.x;
  unsigned long long b = __ballot(m[i] != 0);
  if ((threadIdx.x & 63) == 0) out[i >> 6] = b;
}

// ---------------- prep: Vh [bh][2048 s][128 d] -> Vt [bh][128 d][2048 s] ---
__global__ __launch_bounds__(256) void k_trv(const unsigned short* __restrict__ Vh,
                                             unsigned short* __restrict__ Vt) {
  __shared__ unsigned short t[64][72];
  int bh = blockIdx.z;
  int s0 = blockIdx.x * 64, d0 = blockIdx.y * 64;
  size_t base = (size_t)bh * 2048 * 128;
  int row = threadIdx.x >> 2, c16 = (threadIdx.x & 3) * 16;
  {
    const unsigned short* src = Vh + base + (size_t)(s0 + row) * 128 + d0 + c16;
    ushort8 a0 = *(const ushort8*)src;
    ushort8 a1 = *(const ushort8*)(src + 8);
#pragma unroll
    for (int e = 0; e < 8; ++e) {
      t[c16 + e][row] = a0[e];
      t[c16 + 8 + e][row] = a1[e];
    }
  }
  __syncthreads();
  {
    unsigned short* dst = Vt + base + (size_t)(d0 + row) * 2048 + s0 + c16;
    *(ushort8*)dst = *(const ushort8*)&t[row][c16];
    *(ushort8*)(dst + 8) = *(const ushort8*)&t[row][c16 + 8];
  }
}

// ---------------- GEMM 128x128 tile, BK=64, 4 waves (m97 structure) --------
// A[4096][2048] bf16 row-major, Bt[2048][2048] bf16 = B^T row-major.
// MODE 0: plain bf16 -> [B,H,S,D];  1: LN*scale*rsqrt(D) (Q);  2: LN*scale (K);
// MODE 3: fp32 direct to [4096][2048] (final out-proj).
template <int MODE>
__global__ __launch_bounds__(256) void k_gemm(const unsigned short* __restrict__ A,
                                              const unsigned short* __restrict__ Bt,
                                              void* __restrict__ Cv,
                                              const float* __restrict__ lnsc) {
  constexpr int K = 2048;
  __shared__ __attribute__((aligned(16))) unsigned short sA[128 * 64];
  __shared__ __attribute__((aligned(16))) unsigned short sB[128 * 64];
  __shared__ float sSum[2][128];
  __shared__ float sSq[2][128];
  int tid = threadIdx.x;
  int lane = tid & 63, w = tid >> 6;
  int wr = w >> 1, wc = w & 1;
  int r15 = lane & 15, blk = lane >> 4;
  int n0 = blockIdx.x * 128, m0 = blockIdx.y * 128;
  const unsigned short* Abase = A + (size_t)m0 * K;
  const unsigned short* Bbase = Bt + (size_t)n0 * K;
  f32x4 acc[4][4] = {};

  for (int kt = 0; kt < K; kt += 64) {
#pragma unroll
    for (int i = 0; i < 4; ++i) {   // stage A tile: 1024 16B chunks, XOR-swizzled source
      int c = i * 256 + tid;
      int row = c >> 3, cc = c & 7;
      gload_lds16(Abase + (size_t)row * K + kt + ((cc ^ (row & 7)) * 8), &sA[c * 8]);
    }
#pragma unroll
    for (int i = 0; i < 4; ++i) {   // stage B tile
      int c = i * 256 + tid;
      int row = c >> 3, cc = c & 7;
      gload_lds16(Bbase + (size_t)row * K + kt + ((cc ^ (row & 7)) * 8), &sB[c * 8]);
    }
    __syncthreads();
#pragma unroll
    for (int kk = 0; kk < 2; ++kk) {
      bf16x8 av[4], bv[4];
#pragma unroll
      for (int i = 0; i < 4; ++i) {
        int row = wr * 64 + i * 16 + r15;
        av[i] = *(const bf16x8*)&sA[row * 64 + (((kk * 4 + blk) ^ (row & 7)) * 8)];
      }
#pragma unroll
      for (int j = 0; j < 4; ++j) {
        int row = wc * 64 + j * 16 + r15;
        bv[j] = *(const bf16x8*)&sB[row * 64 + (((kk * 4 + blk) ^ (row & 7)) * 8)];
      }
#pragma unroll
      for (int i = 0; i < 4; ++i)
#pragma unroll
        for (int j = 0; j < 4; ++j) acc[i][j] = MFMA16(av[i], bv[j], acc[i][j]);
    }
    __syncthreads();
  }

  if constexpr (MODE == 3) {
    float* C = (float*)Cv;
#pragma unroll
    for (int i = 0; i < 4; ++i)
#pragma unroll
      for (int r = 0; r < 4; ++r)
#pragma unroll
        for (int j = 0; j < 4; ++j) {
          int rowl = wr * 64 + i * 16 + blk * 4 + r;   // C layout: row=(lane>>4)*4+reg
          int coll = wc * 64 + j * 16 + r15;           //           col=lane&15
          C[(size_t)(m0 + rowl) * 2048 + n0 + coll] = acc[i][j][r];
        }
    return;
  } else {
    if constexpr (MODE == 1 || MODE == 2) {
      // per-row stats over the 128 cols (= head_dim) of this tile
#pragma unroll
      for (int i = 0; i < 4; ++i)
#pragma unroll
        for (int r = 0; r < 4; ++r) {
          float sm = 0.f, sq = 0.f;
#pragma unroll
          for (int j = 0; j < 4; ++j) { float v = acc[i][j][r]; sm += v; sq += v * v; }
          sm += __shfl_xor(sm, 1); sq += __shfl_xor(sq, 1);
          sm += __shfl_xor(sm, 2); sq += __shfl_xor(sq, 2);
          sm += __shfl_xor(sm, 4); sq += __shfl_xor(sq, 4);
          sm += __shfl_xor(sm, 8); sq += __shfl_xor(sq, 8);
          if (r15 == 0) {
            int rowl = wr * 64 + i * 16 + blk * 4 + r;
            sSum[wc][rowl] = sm; sSq[wc][rowl] = sq;
          }
        }
      __syncthreads();
    }
    unsigned short* Hout = (unsigned short*)Cv;
    int h = blockIdx.x;  // BN=128 == D: one head per n-block
#pragma unroll
    for (int i = 0; i < 4; ++i)
#pragma unroll
      for (int r = 0; r < 4; ++r) {
        int rowl = wr * 64 + i * 16 + blk * 4 + r;
        float mean = 0.f, rstd = 1.f;
        if constexpr (MODE == 1 || MODE == 2) {
          float sm = sSum[0][rowl] + sSum[1][rowl];
          float sq = sSq[0][rowl] + sSq[1][rowl];
          mean = sm * 0.0078125f;
          float var = sq * 0.0078125f - mean * mean;
          rstd = rsqrtf(var + 1e-6f);
        }
        int rowg = m0 + rowl;
        int b = rowg >> 11, s = rowg & 2047;
        unsigned short* orow = Hout + (((size_t)b * 16 + h) * 2048 + s) * 128;
#pragma unroll
        for (int j = 0; j < 4; ++j) {
          int d = wc * 64 + j * 16 + r15;
          float v = acc[i][j][r];
          if constexpr (MODE == 1) v = (v - mean) * rstd * lnsc[d] * 0.08838834764831845f;
          if constexpr (MODE == 2) v = (v - mean) * rstd * lnsc[d];
          orow[d] = f2bf(v);
        }
      }
  }
}

// ---------------- flash attention v2: KVBLK=64, GEMM-pattern LDS only ------
// K staged with row-permutation so P slots land on PV A-frag natural k-map;
// V^T (pre-transposed global) staged row-major [d][keys] -> PV B-frag is one
// swizzled ds_read_b128. No in-kernel transpose, no ds_writes.
__global__ __launch_bounds__(256, 4) void k_attn(const unsigned short* __restrict__ Qh,
                                                 const unsigned short* __restrict__ Kh,
                                                 const unsigned short* __restrict__ Vt,
                                                 const unsigned* __restrict__ maskb,
                                                 unsigned short* __restrict__ O) {
  __shared__ __attribute__((aligned(16))) char smem[64 * 132 * 4];  // 33792 B
  unsigned short* sK = (unsigned short*)smem;            // [64 keys][128 d]  16 KB
  unsigned short* sV = (unsigned short*)(smem + 16384);  // [128 d][64 keys]  16 KB
  float* sO = (float*)smem;                              // epilogue overlay [64][132]

  int tid = threadIdx.x, lane = tid & 63, w = tid >> 6;
  int r15 = lane & 15, blk = lane >> 4;
  int bh = blockIdx.y, b = bh >> 4, h = bh & 15;
  int qb = blockIdx.x * 64;
  size_t base = (size_t)bh * (2048 * 128);
  int qrow = qb + w * 16 + r15;

  bf16x8 qf[4];  // Q row hoisted (B-operand fragments), d = kk*32 + blk*8 + j
  {
    const unsigned short* qp = Qh + base + (size_t)qrow * 128 + blk * 8;
#pragma unroll
    for (int kk = 0; kk < 4; ++kk) qf[kk] = *(const bf16x8*)(qp + kk * 32);
  }
  const unsigned* mrow = maskb + ((size_t)b * 2048 + qrow) * 64;

  f32x4 o[8] = {};
  float m = -1e30f, lsum = 0.f;

  for (int kc = 0; kc < 2048; kc += 64) {
#pragma unroll
    for (int i = 0; i < 4; ++i) {  // stage K [64][128]: permuted rows, swizzled cols
      int c = i * 256 + tid;
      int row = c >> 4, cc = c & 15;
      int key = 32 * (row >> 5) + 8 * ((row >> 2) & 3) + 4 * ((row >> 4) & 1) + (row & 3);
      gload_lds16(Kh + base + (size_t)(kc + key) * 128 + ((cc ^ (row & 7)) * 8), &sK[c * 8]);
    }
#pragma unroll
    for (int i = 0; i < 4; ++i) {  // stage V^T [128][64]: swizzled cols
      int c = i * 256 + tid;
      int d = c >> 3, cc = c & 7;
      gload_lds16(Vt + base + (size_t)d * 2048 + kc + ((cc ^ (d & 7)) * 8), &sV[c * 8]);
    }
    __syncthreads();

    // S^T = K . Q^T : 4 row-blocks (16 perm-keys each) x 4 d-blocks
    f32x4 st[4] = {};
#pragma unroll
    for (int kk = 0; kk < 4; ++kk) {
      int cc = (4 * kk + blk) ^ (r15 & 7);
#pragma unroll
      for (int s = 0; s < 4; ++s) {
        bf16x8 kf = *(const bf16x8*)&sK[(16 * s + r15) * 128 + cc * 8];
        st[s] = MFMA16(kf, qf[kk], st[s]);
      }
    }

    // mask + online softmax. lane holds q=r15; slot t=(s*4+r) = actual key
    // 32*(s>>1) + 8*blk + 4*(s&1) + r   (by construction of the K staging perm)
    unsigned mw0 = mrow[kc >> 5], mw1 = mrow[(kc >> 5) + 1];
    float pvv[16];
    float cmax = -1e30f;
#pragma unroll
    for (int t = 0; t < 16; ++t) {
      int s = t >> 2, r = t & 3;
      unsigned mw = (s >> 1) ? mw1 : mw0;
      int bit = 8 * blk + 4 * (s & 1) + r;
      float sv = st[s][r];
      sv = ((mw >> bit) & 1u) ? sv : -1e30f;
      pvv[t] = sv;
      cmax = fmaxf(cmax, sv);
    }
    cmax = fmaxf(cmax, __shfl_xor(cmax, 16));
    cmax = fmaxf(cmax, __shfl_xor(cmax, 32));

    if (!__all(cmax - m <= 8.0f)) {  // defer-max (exact; P bounded by e^8)
      float mnew = fmaxf(m, cmax);
      float fac = __expf(m - mnew);
      lsum *= fac;
      float fr[4];
#pragma unroll
      for (int r = 0; r < 4; ++r) fr[r] = __shfl(fac, blk * 4 + r);
#pragma unroll
      for (int t8 = 0; t8 < 8; ++t8) {
        o[t8][0] *= fr[0]; o[t8][1] *= fr[1]; o[t8][2] *= fr[2]; o[t8][3] *= fr[3];
      }
      m = mnew;
    }

    float csum = 0.f;
#pragma unroll
    for (int t = 0; t < 16; ++t) { pvv[t] = __expf(pvv[t] - m); csum += pvv[t]; }
    csum += __shfl_xor(csum, 16);
    csum += __shfl_xor(csum, 32);
    lsum += csum;

    ushort8 pu0, pu1;
#pragma unroll
    for (int j = 0; j < 8; ++j) { pu0[j] = f2bf(pvv[j]); pu1[j] = f2bf(pvv[8 + j]); }
    bf16x8 pf0 = __builtin_bit_cast(bf16x8, pu0);  // keys  8*blk + j
    bf16x8 pf1 = __builtin_bit_cast(bf16x8, pu1);  // keys 32 + 8*blk + j

    // PV: o[t8] covers d = t8*16 + r15; B-frag = V^T row (16*t8+r15), slot (4m+blk)^swz
#pragma unroll
    for (int t8 = 0; t8 < 8; ++t8) {
      int vr = t8 * 16 + r15;
      bf16x8 v0 = *(const bf16x8*)&sV[vr * 64 + ((blk ^ (r15 & 7)) * 8)];
      bf16x8 v1 = *(const bf16x8*)&sV[vr * 64 + (((4 + blk) ^ (r15 & 7)) * 8)];
      o[t8] = MFMA16(pf0, v0, o[t8]);
      o[t8] = MFMA16(pf1, v1, o[t8]);
    }
    __syncthreads();
  }

  float inv = 1.f / lsum;
  float ir[4];
#pragma unroll
  for (int r = 0; r < 4; ++r) ir[r] = __shfl(inv, blk * 4 + r);
#pragma unroll
  for (int t8 = 0; t8 < 8; ++t8)
#pragma unroll
    for (int r = 0; r < 4; ++r)
      sO[(w * 16 + blk * 4 + r) * 132 + t8 * 16 + r15] = o[t8][r] * ir[r];
  __syncthreads();
  {
    int row = tid >> 2, d0 = (tid & 3) * 32;
    unsigned short* op = O + (size_t)(b * 2048 + qb + row) * 2048 + h * 128 + d0;
#pragma unroll
    for (int g = 0; g < 4; ++g) {
      ushort8 pk;
#pragma unroll
      for (int e = 0; e < 8; ++e) pk[e] = f2bf(sO[row * 132 + d0 + g * 8 + e]);
      *(ushort8*)(op + g * 8) = pk;
    }
  }
}

// ---------------------------------------------------------------------------
extern "C" void kernel_launch(void* const* d_in, const int* in_sizes, int n_in,
                              void* d_out, int out_size, void* d_ws, size_t ws_size,
                              hipStream_t stream) {
  const float* q      = (const float*)d_in[0];
  const float* kv     = (const float*)d_in[1];
  const float* q_pos  = (const float*)d_in[2];
  const float* kv_pos = (const float*)d_in[3];
  const int*   mask   = (const int*)d_in[4];
  const float* wq     = (const float*)d_in[5];
  const float* wk     = (const float*)d_in[6];
  const float* wv     = (const float*)d_in[7];
  const float* qls    = (const float*)d_in[8];
  const float* kls    = (const float*)d_in[9];
  const float* wo     = (const float*)d_in[10];

  char* ws = (char*)d_ws;
  const size_t SZ_ACT = (size_t)4096 * 2048 * 2;  // 16 MiB
  const size_t SZ_W   = (size_t)2048 * 2048 * 2;  // 8 MiB
  unsigned short* a_q = (unsigned short*)(ws);
  unsigned short* a_k = (unsigned short*)(ws + SZ_ACT);
  unsigned short* a_v = (unsigned short*)(ws + 2 * SZ_ACT);
  unsigned short* Qh  = (unsigned short*)(ws + 3 * SZ_ACT);
  unsigned short* Kh  = (unsigned short*)(ws + 4 * SZ_ACT);
  unsigned short* Vh  = (unsigned short*)(ws + 5 * SZ_ACT);
  unsigned short* wqt = (unsigned short*)(ws + 6 * SZ_ACT);
  unsigned short* wkt = (unsigned short*)(ws + 6 * SZ_ACT + SZ_W);
  unsigned short* wvt = (unsigned short*)(ws + 6 * SZ_ACT + 2 * SZ_W);
  unsigned short* wot = (unsigned short*)(ws + 6 * SZ_ACT + 3 * SZ_W);
  unsigned*       mkb = (unsigned*)(ws + 6 * SZ_ACT + 4 * SZ_W);
  unsigned short* Ob  = a_q;  // a_q dead after Q-projection; reuse for attn out
  unsigned short* Vtr = a_k;  // a_k dead after K-projection; reuse for V^T

  const size_t NEED = 6 * SZ_ACT + 4 * SZ_W + (size_t)2 * 2048 * 64 * 4;
  if (ws_size < NEED) return;  // leave d_out poisoned -> visible failure

  k_cvt<<<8192, 256, 0, stream>>>((const float4v*)q,  (const float4v*)q_pos,  (ushort4v*)a_q, 2097152);
  k_cvt<<<8192, 256, 0, stream>>>((const float4v*)kv, (const float4v*)kv_pos, (ushort4v*)a_k, 2097152);
  k_cvt<<<8192, 256, 0, stream>>>((const float4v*)kv, nullptr,                (ushort4v*)a_v, 2097152);
  k_tr<<<dim3(64, 64, 4), 256, 0, stream>>>(wq, wk, wv, wo, wqt, wkt, wvt, wot);
  k_mask<<<32768, 256, 0, stream>>>(mask, (unsigned long long*)mkb);

  k_gemm<1><<<dim3(16, 32), 256, 0, stream>>>(a_q, wqt, Qh, qls);
  k_gemm<2><<<dim3(16, 32), 256, 0, stream>>>(a_k, wkt, Kh, kls);
  k_gemm<0><<<dim3(16, 32), 256, 0, stream>>>(a_v, wvt, Vh, nullptr);

  k_trv<<<dim3(32, 2, 32), 256, 0, stream>>>(Vh, Vtr);

  k_attn<<<dim3(32, 32), 256, 0, stream>>>(Qh, Kh, Vtr, mkb, Ob);

  k_gemm<3><<<dim3(16, 32), 256, 0, stream>>>(Ob, wot, d_out, nullptr);
}

// Round 4
// 362.032 us; speedup vs baseline: 1.4706x; 1.0320x over previous
//
#include <hip/hip_runtime.h>
#include <hip/hip_bf16.h>

// ---------------------------------------------------------------------------
// AttentionBlock: qkv-proj (+LN on q,k) -> masked flash attention -> out-proj
// B=2, S=2048, E=2048, H=16, D=128. All matmuls bf16 MFMA (16x16x32), fp32 acc.
// Softmax runs in exp2 domain (log2e folded into Q-projection epilogue).
// ---------------------------------------------------------------------------

typedef __attribute__((ext_vector_type(8))) __bf16 bf16x8;
typedef __attribute__((ext_vector_type(4))) float f32x4;
typedef __attribute__((ext_vector_type(8))) unsigned short ushort8;
typedef __attribute__((ext_vector_type(4))) unsigned short ushort4v;
typedef __attribute__((ext_vector_type(4))) unsigned uint4v;
typedef __attribute__((ext_vector_type(4))) float float4v;

#define MFMA16(a, b, c) __builtin_amdgcn_mfma_f32_16x16x32_bf16((a), (b), (c), 0, 0, 0)

__device__ __forceinline__ unsigned short f2bf(float f) {
  unsigned u = __builtin_bit_cast(unsigned, f);
  u += 0x7fffu + ((u >> 16) & 1u);           // RNE
  return (unsigned short)(u >> 16);
}

__device__ __forceinline__ unsigned pkbf(float lo, float hi) {  // bf16(lo)|bf16(hi)<<16
  unsigned d;
  asm("v_cvt_pk_bf16_f32 %0, %1, %2" : "=v"(d) : "v"(lo), "v"(hi));
  return d;
}

__device__ __forceinline__ float max3f(float a, float b, float c) {
  float d;
  asm("v_max3_f32 %0, %1, %2, %3" : "=v"(d) : "v"(a), "v"(b), "v"(c));
  return d;
}

__device__ __forceinline__ float exp2a(float x) {  // 2^x
  float d;
  asm("v_exp_f32 %0, %1" : "=v"(d) : "v"(x));
  return d;
}

__device__ __forceinline__ void gload_lds16(const void* g, void* l) {
  __builtin_amdgcn_global_load_lds(
      (const __attribute__((address_space(1))) void*)g,
      (__attribute__((address_space(3))) void*)l, 16, 0, 0);
}

// ---------------- prep: elementwise add + fp32->bf16 -----------------------
__global__ __launch_bounds__(256) void k_cvt(const float4v* __restrict__ x,
                                             const float4v* __restrict__ y,
                                             ushort4v* __restrict__ o, int n4) {
  int i = blockIdx.x * 256 + threadIdx.x;
  if (i >= n4) return;
  float4v a = x[i];
  if (y) { float4v b = y[i]; a = a + b; }
  ushort4v r;
  r[0] = f2bf(a[0]); r[1] = f2bf(a[1]); r[2] = f2bf(a[2]); r[3] = f2bf(a[3]);
  o[i] = r;
}

// ---------------- prep: kv -> a_k (kv+kv_pos) and a_v (kv) in one pass -----
__global__ __launch_bounds__(256) void k_cvt2(const float4v* __restrict__ x,
                                              const float4v* __restrict__ y,
                                              ushort4v* __restrict__ oa,
                                              ushort4v* __restrict__ ob, int n4) {
  int i = blockIdx.x * 256 + threadIdx.x;
  if (i >= n4) return;
  float4v a = x[i];
  float4v s = a + y[i];
  ushort4v ra, rb;
  ra[0] = f2bf(s[0]); ra[1] = f2bf(s[1]); ra[2] = f2bf(s[2]); ra[3] = f2bf(s[3]);
  rb[0] = f2bf(a[0]); rb[1] = f2bf(a[1]); rb[2] = f2bf(a[2]); rb[3] = f2bf(a[3]);
  oa[i] = ra; ob[i] = rb;
}

// ---------------- prep: weight transpose fp32[K][N] -> bf16[N][K] ----------
__global__ __launch_bounds__(256) void k_tr(const float* __restrict__ s0, const float* __restrict__ s1,
                                            const float* __restrict__ s2, const float* __restrict__ s3,
                                            unsigned short* __restrict__ d0, unsigned short* __restrict__ d1,
                                            unsigned short* __restrict__ d2, unsigned short* __restrict__ d3) {
  __shared__ float t[32][33];
  const float* S; unsigned short* D;
  switch (blockIdx.z) {
    case 0: S = s0; D = d0; break;
    case 1: S = s1; D = d1; break;
    case 2: S = s2; D = d2; break;
    default: S = s3; D = d3; break;
  }
  int x = threadIdx.x & 31, y = threadIdx.x >> 5;
  int r0 = blockIdx.y * 32, c0 = blockIdx.x * 32;
#pragma unroll
  for (int i = 0; i < 4; ++i) t[y + 8 * i][x] = S[(size_t)(r0 + y + 8 * i) * 2048 + c0 + x];
  __syncthreads();
#pragma unroll
  for (int i = 0; i < 4; ++i)
    D[(size_t)(c0 + y + 8 * i) * 2048 + r0 + x] = f2bf(t[x][y + 8 * i]);
}

// ---------------- prep: mask int32 -> bitmask (1 bit/key) ------------------
__global__ __launch_bounds__(256) void k_mask(const int* __restrict__ m,
                                              unsigned long long* __restrict__ out) {
  int i = blockIdx.x * 256 + threadIdx.x;
  unsigned long long b = __ballot(m[i] != 0);
  if ((threadIdx.x & 63) == 0) out[i >> 6] = b;
}

// ---------------- prep: Vh [bh][2048 s][128 d] -> Vt [bh][128 d][2048 s] ---
__global__ __launch_bounds__(256) void k_trv(const unsigned short* __restrict__ Vh,
                                             unsigned short* __restrict__ Vt) {
  __shared__ unsigned short t[64][72];
  int bh = blockIdx.z;
  int s0 = blockIdx.x * 64, d0 = blockIdx.y * 64;
  size_t base = (size_t)bh * 2048 * 128;
  int row = threadIdx.x >> 2, c16 = (threadIdx.x & 3) * 16;
  {
    const unsigned short* src = Vh + base + (size_t)(s0 + row) * 128 + d0 + c16;
    ushort8 a0 = *(const ushort8*)src;
    ushort8 a1 = *(const ushort8*)(src + 8);
#pragma unroll
    for (int e = 0; e < 8; ++e) {
      t[c16 + e][row] = a0[e];
      t[c16 + 8 + e][row] = a1[e];
    }
  }
  __syncthreads();
  {
    unsigned short* dst = Vt + base + (size_t)(d0 + row) * 2048 + s0 + c16;
    *(ushort8*)dst = *(const ushort8*)&t[row][c16];
    *(ushort8*)(dst + 8) = *(const ushort8*)&t[row][c16 + 8];
  }
}

// ---------------- GEMM 128x128 tile, BK=64, 4 waves (m97 structure) --------
// MODE 0: plain bf16 -> [B,H,S,D];  1: LN*scale*rsqrt(D)*log2e (Q);
// MODE 2: LN*scale (K);  3: fp32 direct to [4096][2048] (final out-proj).
template <int MODE>
__global__ __launch_bounds__(256) void k_gemm(const unsigned short* __restrict__ A,
                                              const unsigned short* __restrict__ Bt,
                                              void* __restrict__ Cv,
                                              const float* __restrict__ lnsc) {
  constexpr int K = 2048;
  __shared__ __attribute__((aligned(16))) unsigned short sA[128 * 64];
  __shared__ __attribute__((aligned(16))) unsigned short sB[128 * 64];
  __shared__ float sSum[2][128];
  __shared__ float sSq[2][128];
  int tid = threadIdx.x;
  int lane = tid & 63, w = tid >> 6;
  int wr = w >> 1, wc = w & 1;
  int r15 = lane & 15, blk = lane >> 4;
  int n0 = blockIdx.x * 128, m0 = blockIdx.y * 128;
  const unsigned short* Abase = A + (size_t)m0 * K;
  const unsigned short* Bbase = Bt + (size_t)n0 * K;
  f32x4 acc[4][4] = {};

  for (int kt = 0; kt < K; kt += 64) {
#pragma unroll
    for (int i = 0; i < 4; ++i) {   // stage A tile: 1024 16B chunks, XOR-swizzled source
      int c = i * 256 + tid;
      int row = c >> 3, cc = c & 7;
      gload_lds16(Abase + (size_t)row * K + kt + ((cc ^ (row & 7)) * 8), &sA[c * 8]);
    }
#pragma unroll
    for (int i = 0; i < 4; ++i) {   // stage B tile
      int c = i * 256 + tid;
      int row = c >> 3, cc = c & 7;
      gload_lds16(Bbase + (size_t)row * K + kt + ((cc ^ (row & 7)) * 8), &sB[c * 8]);
    }
    __syncthreads();
#pragma unroll
    for (int kk = 0; kk < 2; ++kk) {
      bf16x8 av[4], bv[4];
#pragma unroll
      for (int i = 0; i < 4; ++i) {
        int row = wr * 64 + i * 16 + r15;
        av[i] = *(const bf16x8*)&sA[row * 64 + (((kk * 4 + blk) ^ (row & 7)) * 8)];
      }
#pragma unroll
      for (int j = 0; j < 4; ++j) {
        int row = wc * 64 + j * 16 + r15;
        bv[j] = *(const bf16x8*)&sB[row * 64 + (((kk * 4 + blk) ^ (row & 7)) * 8)];
      }
#pragma unroll
      for (int i = 0; i < 4; ++i)
#pragma unroll
        for (int j = 0; j < 4; ++j) acc[i][j] = MFMA16(av[i], bv[j], acc[i][j]);
    }
    __syncthreads();
  }

  if constexpr (MODE == 3) {
    float* C = (float*)Cv;
#pragma unroll
    for (int i = 0; i < 4; ++i)
#pragma unroll
      for (int r = 0; r < 4; ++r)
#pragma unroll
        for (int j = 0; j < 4; ++j) {
          int rowl = wr * 64 + i * 16 + blk * 4 + r;   // C layout: row=(lane>>4)*4+reg
          int coll = wc * 64 + j * 16 + r15;           //           col=lane&15
          C[(size_t)(m0 + rowl) * 2048 + n0 + coll] = acc[i][j][r];
        }
    return;
  } else {
    if constexpr (MODE == 1 || MODE == 2) {
      // per-row stats over the 128 cols (= head_dim) of this tile
#pragma unroll
      for (int i = 0; i < 4; ++i)
#pragma unroll
        for (int r = 0; r < 4; ++r) {
          float sm = 0.f, sq = 0.f;
#pragma unroll
          for (int j = 0; j < 4; ++j) { float v = acc[i][j][r]; sm += v; sq += v * v; }
          sm += __shfl_xor(sm, 1); sq += __shfl_xor(sq, 1);
          sm += __shfl_xor(sm, 2); sq += __shfl_xor(sq, 2);
          sm += __shfl_xor(sm, 4); sq += __shfl_xor(sq, 4);
          sm += __shfl_xor(sm, 8); sq += __shfl_xor(sq, 8);
          if (r15 == 0) {
            int rowl = wr * 64 + i * 16 + blk * 4 + r;
            sSum[wc][rowl] = sm; sSq[wc][rowl] = sq;
          }
        }
      __syncthreads();
    }
    unsigned short* Hout = (unsigned short*)Cv;
    int h = blockIdx.x;  // BN=128 == D: one head per n-block
#pragma unroll
    for (int i = 0; i < 4; ++i)
#pragma unroll
      for (int r = 0; r < 4; ++r) {
        int rowl = wr * 64 + i * 16 + blk * 4 + r;
        float mean = 0.f, rstd = 1.f;
        if constexpr (MODE == 1 || MODE == 2) {
          float sm = sSum[0][rowl] + sSum[1][rowl];
          float sq = sSq[0][rowl] + sSq[1][rowl];
          mean = sm * 0.0078125f;
          float var = sq * 0.0078125f - mean * mean;
          rstd = rsqrtf(var + 1e-6f);
        }
        int rowg = m0 + rowl;
        int b = rowg >> 11, s = rowg & 2047;
        unsigned short* orow = Hout + (((size_t)b * 16 + h) * 2048 + s) * 128;
#pragma unroll
        for (int j = 0; j < 4; ++j) {
          int d = wc * 64 + j * 16 + r15;
          float v = acc[i][j][r];
          // log2e folded in: attention softmax runs in exp2 domain
          if constexpr (MODE == 1)
            v = (v - mean) * rstd * lnsc[d] * (0.08838834764831845f * 1.4426950408889634f);
          if constexpr (MODE == 2) v = (v - mean) * rstd * lnsc[d];
          orow[d] = f2bf(v);
        }
      }
  }
}

// ---------------- flash attention v3: exp2-domain lean softmax -------------
// K staged with row-permutation so P slots land on PV A-frag natural k-map;
// V^T (pre-transposed global) staged row-major [d][keys].
__global__ __launch_bounds__(256, 4) void k_attn(const unsigned short* __restrict__ Qh,
                                                 const unsigned short* __restrict__ Kh,
                                                 const unsigned short* __restrict__ Vt,
                                                 const unsigned* __restrict__ maskb,
                                                 unsigned short* __restrict__ O) {
  __shared__ __attribute__((aligned(16))) char smem[64 * 132 * 4];  // 33792 B
  unsigned short* sK = (unsigned short*)smem;            // [64 keys][128 d]  16 KB
  unsigned short* sV = (unsigned short*)(smem + 16384);  // [128 d][64 keys]  16 KB
  float* sO = (float*)smem;                              // epilogue overlay [64][132]

  int tid = threadIdx.x, w = tid >> 6;
  int lane = tid & 63;
  int r15 = lane & 15, blk = lane >> 4;
  int bh = blockIdx.y, b = bh >> 4, h = bh & 15;
  int qb = blockIdx.x * 64;
  size_t base = (size_t)bh * (2048 * 128);
  int qrow = qb + w * 16 + r15;

  bf16x8 qf[4];  // Q row hoisted (B-operand fragments), d = kk*32 + blk*8 + j
  {
    const unsigned short* qp = Qh + base + (size_t)qrow * 128 + blk * 8;
#pragma unroll
    for (int kk = 0; kk < 4; ++kk) qf[kk] = *(const bf16x8*)(qp + kk * 32);
  }
  const unsigned* mrow = maskb + ((size_t)b * 2048 + qrow) * 64;

  // hoisted staging pointers (bump per iter)
  const unsigned short* kp[4];
  const unsigned short* vp[4];
  unsigned short* kl[4];
  unsigned short* vl[4];
#pragma unroll
  for (int i = 0; i < 4; ++i) {
    int c = i * 256 + tid;
    int krow = c >> 4, kcc = c & 15;
    int key = 32 * (krow >> 5) + 8 * ((krow >> 2) & 3) + 4 * ((krow >> 4) & 1) + (krow & 3);
    kp[i] = Kh + base + (size_t)key * 128 + ((kcc ^ (krow & 7)) * 8);
    kl[i] = &sK[c * 8];
    int d = c >> 3, c8 = c & 7;
    vp[i] = Vt + base + (size_t)d * 2048 + ((c8 ^ (d & 7)) * 8);
    vl[i] = &sV[c * 8];
  }

  f32x4 o[8] = {};
  float m = -1e30f, lsum = 0.f;  // lsum: per-lane partial (reduced once at end)

  for (int kc = 0; kc < 2048; kc += 64) {
#pragma unroll
    for (int i = 0; i < 4; ++i) { gload_lds16(kp[i], kl[i]); kp[i] += 64 * 128; }
#pragma unroll
    for (int i = 0; i < 4; ++i) { gload_lds16(vp[i], vl[i]); vp[i] += 64; }
    __syncthreads();

    // S^T = K . Q^T : 4 row-blocks (16 perm-keys each) x 4 d-blocks
    f32x4 st[4] = {};
#pragma unroll
    for (int kk = 0; kk < 4; ++kk) {
      int cc = (4 * kk + blk) ^ (r15 & 7);
#pragma unroll
      for (int s = 0; s < 4; ++s) {
        bf16x8 kf = *(const bf16x8*)&sK[(16 * s + r15) * 128 + cc * 8];
        st[s] = MFMA16(kf, qf[kk], st[s]);
      }
    }

    // mask + online softmax (exp2 domain). lane holds q=r15; slot t=(s*4+r) is
    // key 32*(s>>1) + 8*blk + 4*(s&1) + r  (by construction of the K perm)
    unsigned mws0 = mrow[kc >> 5] >> (blk * 8);
    unsigned mws1 = mrow[(kc >> 5) + 1] >> (blk * 8);
    float pvv[16];
#pragma unroll
    for (int t = 0; t < 16; ++t) {
      int s = t >> 2, r = t & 3;
      unsigned mws = (s & 2) ? mws1 : mws0;
      int bit = 4 * (s & 1) + r;  // compile-time constant per t
      pvv[t] = ((mws >> bit) & 1u) ? st[s][r] : -1e30f;
    }
    float c0 = max3f(pvv[0], pvv[1], pvv[2]);
    float c1 = max3f(pvv[3], pvv[4], pvv[5]);
    float c2 = max3f(pvv[6], pvv[7], pvv[8]);
    float c3 = max3f(pvv[9], pvv[10], pvv[11]);
    float c4 = max3f(pvv[12], pvv[13], pvv[14]);
    float cmax = fmaxf(max3f(c0, c1, c2), max3f(c3, c4, pvv[15]));
    cmax = fmaxf(cmax, __shfl_xor(cmax, 16));
    cmax = fmaxf(cmax, __shfl_xor(cmax, 32));

    if (!__all(cmax - m <= 11.5f)) {  // defer-max: P bounded by 2^11.5
      float mnew = fmaxf(m, cmax);
      float fac = exp2a(m - mnew);
      lsum *= fac;
      float fr[4];
#pragma unroll
      for (int r = 0; r < 4; ++r) fr[r] = __shfl(fac, blk * 4 + r);
#pragma unroll
      for (int t8 = 0; t8 < 8; ++t8) {
        o[t8][0] *= fr[0]; o[t8][1] *= fr[1]; o[t8][2] *= fr[2]; o[t8][3] *= fr[3];
      }
      m = mnew;
    }

#pragma unroll
    for (int t = 0; t < 16; ++t) pvv[t] = exp2a(pvv[t] - m);
    // balanced tree sum into per-lane partial
    float s0 = (pvv[0] + pvv[1]) + (pvv[2] + pvv[3]);
    float s1 = (pvv[4] + pvv[5]) + (pvv[6] + pvv[7]);
    float s2 = (pvv[8] + pvv[9]) + (pvv[10] + pvv[11]);
    float s3 = (pvv[12] + pvv[13]) + (pvv[14] + pvv[15]);
    lsum += (s0 + s1) + (s2 + s3);

    uint4v w0, w1;
#pragma unroll
    for (int j = 0; j < 4; ++j) {
      w0[j] = pkbf(pvv[2 * j], pvv[2 * j + 1]);
      w1[j] = pkbf(pvv[8 + 2 * j], pvv[9 + 2 * j]);
    }
    bf16x8 pf0 = __builtin_bit_cast(bf16x8, w0);  // keys  8*blk + j
    bf16x8 pf1 = __builtin_bit_cast(bf16x8, w1);  // keys 32 + 8*blk + j

    // PV: o[t8] covers d = t8*16 + r15; B-frag = V^T row (16*t8+r15)
#pragma unroll
    for (int t8 = 0; t8 < 8; ++t8) {
      int vr = t8 * 16 + r15;
      bf16x8 v0 = *(const bf16x8*)&sV[vr * 64 + ((blk ^ (r15 & 7)) * 8)];
      bf16x8 v1 = *(const bf16x8*)&sV[vr * 64 + (((4 + blk) ^ (r15 & 7)) * 8)];
      o[t8] = MFMA16(pf0, v0, o[t8]);
      o[t8] = MFMA16(pf1, v1, o[t8]);
    }
    __syncthreads();
  }

  lsum += __shfl_xor(lsum, 16);
  lsum += __shfl_xor(lsum, 32);
  float inv = 1.f / lsum;
  float ir[4];
#pragma unroll
  for (int r = 0; r < 4; ++r) ir[r] = __shfl(inv, blk * 4 + r);
#pragma unroll
  for (int t8 = 0; t8 < 8; ++t8)
#pragma unroll
    for (int r = 0; r < 4; ++r)
      sO[(w * 16 + blk * 4 + r) * 132 + t8 * 16 + r15] = o[t8][r] * ir[r];
  __syncthreads();
  {
    int row = tid >> 2, d0 = (tid & 3) * 32;
    unsigned short* op = O + (size_t)(b * 2048 + qb + row) * 2048 + h * 128 + d0;
#pragma unroll
    for (int g = 0; g < 4; ++g) {
      ushort8 pk;
#pragma unroll
      for (int e = 0; e < 8; ++e) pk[e] = f2bf(sO[row * 132 + d0 + g * 8 + e]);
      *(ushort8*)(op + g * 8) = pk;
    }
  }
}

// ---------------------------------------------------------------------------
extern "C" void kernel_launch(void* const* d_in, const int* in_sizes, int n_in,
                              void* d_out, int out_size, void* d_ws, size_t ws_size,
                              hipStream_t stream) {
  const float* q      = (const float*)d_in[0];
  const float* kv     = (const float*)d_in[1];
  const float* q_pos  = (const float*)d_in[2];
  const float* kv_pos = (const float*)d_in[3];
  const int*   mask   = (const int*)d_in[4];
  const float* wq     = (const float*)d_in[5];
  const float* wk     = (const float*)d_in[6];
  const float* wv     = (const float*)d_in[7];
  const float* qls    = (const float*)d_in[8];
  const float* kls    = (const float*)d_in[9];
  const float* wo     = (const float*)d_in[10];

  char* ws = (char*)d_ws;
  const size_t SZ_ACT = (size_t)4096 * 2048 * 2;  // 16 MiB
  const size_t SZ_W   = (size_t)2048 * 2048 * 2;  // 8 MiB
  unsigned short* a_q = (unsigned short*)(ws);
  unsigned short* a_k = (unsigned short*)(ws + SZ_ACT);
  unsigned short* a_v = (unsigned short*)(ws + 2 * SZ_ACT);
  unsigned short* Qh  = (unsigned short*)(ws + 3 * SZ_ACT);
  unsigned short* Kh  = (unsigned short*)(ws + 4 * SZ_ACT);
  unsigned short* Vh  = (unsigned short*)(ws + 5 * SZ_ACT);
  unsigned short* wqt = (unsigned short*)(ws + 6 * SZ_ACT);
  unsigned short* wkt = (unsigned short*)(ws + 6 * SZ_ACT + SZ_W);
  unsigned short* wvt = (unsigned short*)(ws + 6 * SZ_ACT + 2 * SZ_W);
  unsigned short* wot = (unsigned short*)(ws + 6 * SZ_ACT + 3 * SZ_W);
  unsigned*       mkb = (unsigned*)(ws + 6 * SZ_ACT + 4 * SZ_W);
  unsigned short* Ob  = a_q;  // a_q dead after Q-projection; reuse for attn out
  unsigned short* Vtr = a_k;  // a_k dead after K-projection; reuse for V^T

  const size_t NEED = 6 * SZ_ACT + 4 * SZ_W + (size_t)2 * 2048 * 64 * 4;
  if (ws_size < NEED) return;  // leave d_out poisoned -> visible failure

  k_cvt<<<8192, 256, 0, stream>>>((const float4v*)q, (const float4v*)q_pos, (ushort4v*)a_q, 2097152);
  k_cvt2<<<8192, 256, 0, stream>>>((const float4v*)kv, (const float4v*)kv_pos,
                                   (ushort4v*)a_k, (ushort4v*)a_v, 2097152);
  k_tr<<<dim3(64, 64, 4), 256, 0, stream>>>(wq, wk, wv, wo, wqt, wkt, wvt, wot);
  k_mask<<<32768, 256, 0, stream>>>(mask, (unsigned long long*)mkb);

  k_gemm<1><<<dim3(16, 32), 256, 0, stream>>>(a_q, wqt, Qh, qls);
  k_gemm<2><<<dim3(16, 32), 256, 0, stream>>>(a_k, wkt, Kh, kls);
  k_gemm<0><<<dim3(16, 32), 256, 0, stream>>>(a_v, wvt, Vh, nullptr);

  k_trv<<<dim3(32, 2, 32), 256, 0, stream>>>(Vh, Vtr);

  k_attn<<<dim3(32, 32), 256, 0, stream>>>(Qh, Kh, Vtr, mkb, Ob);

  k_gemm<3><<<dim3(16, 32), 256, 0, stream>>>(Ob, wot, d_out, nullptr);
}

// Round 5
// 353.140 us; speedup vs baseline: 1.5076x; 1.0252x over previous
//
#include <hip/hip_runtime.h>
#include <hip/hip_bf16.h>

// ---------------------------------------------------------------------------
// AttentionBlock: qkv-proj (+LN on q,k) -> masked flash attention -> out-proj
// B=2, S=2048, E=2048, H=16, D=128. All matmuls bf16 MFMA (16x16x32), fp32 acc.
// Softmax runs in exp2 domain (log2e folded into Q-projection epilogue).
// ---------------------------------------------------------------------------

typedef __attribute__((ext_vector_type(8))) __bf16 bf16x8;
typedef __attribute__((ext_vector_type(4))) float f32x4;
typedef __attribute__((ext_vector_type(8))) unsigned short ushort8;
typedef __attribute__((ext_vector_type(4))) unsigned short ushort4v;
typedef __attribute__((ext_vector_type(4))) unsigned uint4v;
typedef __attribute__((ext_vector_type(4))) float float4v;

#define MFMA16(a, b, c) __builtin_amdgcn_mfma_f32_16x16x32_bf16((a), (b), (c), 0, 0, 0)

__device__ __forceinline__ unsigned short f2bf(float f) {
  unsigned u = __builtin_bit_cast(unsigned, f);
  u += 0x7fffu + ((u >> 16) & 1u);           // RNE
  return (unsigned short)(u >> 16);
}

__device__ __forceinline__ unsigned pkbf(float lo, float hi) {  // bf16(lo)|bf16(hi)<<16
  unsigned d;
  asm("v_cvt_pk_bf16_f32 %0, %1, %2" : "=v"(d) : "v"(lo), "v"(hi));
  return d;
}

__device__ __forceinline__ float max3f(float a, float b, float c) {
  float d;
  asm("v_max3_f32 %0, %1, %2, %3" : "=v"(d) : "v"(a), "v"(b), "v"(c));
  return d;
}

__device__ __forceinline__ float exp2a(float x) {  // 2^x
  float d;
  asm("v_exp_f32 %0, %1" : "=v"(d) : "v"(x));
  return d;
}

__device__ __forceinline__ void gload_lds16(const void* g, void* l) {
  __builtin_amdgcn_global_load_lds(
      (const __attribute__((address_space(1))) void*)g,
      (__attribute__((address_space(3))) void*)l, 16, 0, 0);
}

// ---------------- prep: elementwise add + fp32->bf16 -----------------------
__global__ __launch_bounds__(256) void k_cvt(const float4v* __restrict__ x,
                                             const float4v* __restrict__ y,
                                             ushort4v* __restrict__ o, int n4) {
  int i = blockIdx.x * 256 + threadIdx.x;
  if (i >= n4) return;
  float4v a = x[i];
  if (y) { float4v b = y[i]; a = a + b; }
  ushort4v r;
  r[0] = f2bf(a[0]); r[1] = f2bf(a[1]); r[2] = f2bf(a[2]); r[3] = f2bf(a[3]);
  o[i] = r;
}

// ---------------- prep: kv -> a_k (kv+kv_pos) and a_v (kv) in one pass -----
__global__ __launch_bounds__(256) void k_cvt2(const float4v* __restrict__ x,
                                              const float4v* __restrict__ y,
                                              ushort4v* __restrict__ oa,
                                              ushort4v* __restrict__ ob, int n4) {
  int i = blockIdx.x * 256 + threadIdx.x;
  if (i >= n4) return;
  float4v a = x[i];
  float4v s = a + y[i];
  ushort4v ra, rb;
  ra[0] = f2bf(s[0]); ra[1] = f2bf(s[1]); ra[2] = f2bf(s[2]); ra[3] = f2bf(s[3]);
  rb[0] = f2bf(a[0]); rb[1] = f2bf(a[1]); rb[2] = f2bf(a[2]); rb[3] = f2bf(a[3]);
  oa[i] = ra; ob[i] = rb;
}

// ---------------- prep: weight transpose fp32[K][N] -> bf16[N][K] ----------
__global__ __launch_bounds__(256) void k_tr(const float* __restrict__ s0, const float* __restrict__ s1,
                                            const float* __restrict__ s2, const float* __restrict__ s3,
                                            unsigned short* __restrict__ d0, unsigned short* __restrict__ d1,
                                            unsigned short* __restrict__ d2, unsigned short* __restrict__ d3) {
  __shared__ float t[32][33];
  const float* S; unsigned short* D;
  switch (blockIdx.z) {
    case 0: S = s0; D = d0; break;
    case 1: S = s1; D = d1; break;
    case 2: S = s2; D = d2; break;
    default: S = s3; D = d3; break;
  }
  int x = threadIdx.x & 31, y = threadIdx.x >> 5;
  int r0 = blockIdx.y * 32, c0 = blockIdx.x * 32;
#pragma unroll
  for (int i = 0; i < 4; ++i) t[y + 8 * i][x] = S[(size_t)(r0 + y + 8 * i) * 2048 + c0 + x];
  __syncthreads();
#pragma unroll
  for (int i = 0; i < 4; ++i)
    D[(size_t)(c0 + y + 8 * i) * 2048 + r0 + x] = f2bf(t[x][y + 8 * i]);
}

// ---------------- prep: mask int32 -> bitmask (1 bit/key) ------------------
__global__ __launch_bounds__(256) void k_mask(const int* __restrict__ m,
                                              unsigned long long* __restrict__ out) {
  int i = blockIdx.x * 256 + threadIdx.x;
  unsigned long long b = __ballot(m[i] != 0);
  if ((threadIdx.x & 63) == 0) out[i >> 6] = b;
}

// ---------------- prep: Vh [bh][2048 s][128 d] -> Vt [bh][128 d][2048 s] ---
__global__ __launch_bounds__(256) void k_trv(const unsigned short* __restrict__ Vh,
                                             unsigned short* __restrict__ Vt) {
  __shared__ unsigned short t[64][72];
  int bh = blockIdx.z;
  int s0 = blockIdx.x * 64, d0 = blockIdx.y * 64;
  size_t base = (size_t)bh * 2048 * 128;
  int row = threadIdx.x >> 2, c16 = (threadIdx.x & 3) * 16;
  {
    const unsigned short* src = Vh + base + (size_t)(s0 + row) * 128 + d0 + c16;
    ushort8 a0 = *(const ushort8*)src;
    ushort8 a1 = *(const ushort8*)(src + 8);
#pragma unroll
    for (int e = 0; e < 8; ++e) {
      t[c16 + e][row] = a0[e];
      t[c16 + 8 + e][row] = a1[e];
    }
  }
  __syncthreads();
  {
    unsigned short* dst = Vt + base + (size_t)(d0 + row) * 2048 + s0 + c16;
    *(ushort8*)dst = *(const ushort8*)&t[row][c16];
    *(ushort8*)(dst + 8) = *(const ushort8*)&t[row][c16 + 8];
  }
}

// ---------------- GEMM 128x128 tile, BK=64, 4 waves (m97 structure) --------
// MODE 0: plain bf16 -> [B,H,S,D];  1: LN*scale*rsqrt(D)*log2e (Q);
// MODE 2: LN*scale (K);  3: fp32 direct to [4096][2048] (final out-proj).
template <int MODE>
__global__ __launch_bounds__(256) void k_gemm(const unsigned short* __restrict__ A,
                                              const unsigned short* __restrict__ Bt,
                                              void* __restrict__ Cv,
                                              const float* __restrict__ lnsc) {
  constexpr int K = 2048;
  __shared__ __attribute__((aligned(16))) unsigned short sA[128 * 64];
  __shared__ __attribute__((aligned(16))) unsigned short sB[128 * 64];
  __shared__ float sSum[2][128];
  __shared__ float sSq[2][128];
  int tid = threadIdx.x;
  int lane = tid & 63, w = tid >> 6;
  int wr = w >> 1, wc = w & 1;
  int r15 = lane & 15, blk = lane >> 4;
  int n0 = blockIdx.x * 128, m0 = blockIdx.y * 128;
  const unsigned short* Abase = A + (size_t)m0 * K;
  const unsigned short* Bbase = Bt + (size_t)n0 * K;
  f32x4 acc[4][4] = {};

  for (int kt = 0; kt < K; kt += 64) {
#pragma unroll
    for (int i = 0; i < 4; ++i) {   // stage A tile: 1024 16B chunks, XOR-swizzled source
      int c = i * 256 + tid;
      int row = c >> 3, cc = c & 7;
      gload_lds16(Abase + (size_t)row * K + kt + ((cc ^ (row & 7)) * 8), &sA[c * 8]);
    }
#pragma unroll
    for (int i = 0; i < 4; ++i) {   // stage B tile
      int c = i * 256 + tid;
      int row = c >> 3, cc = c & 7;
      gload_lds16(Bbase + (size_t)row * K + kt + ((cc ^ (row & 7)) * 8), &sB[c * 8]);
    }
    __syncthreads();
#pragma unroll
    for (int kk = 0; kk < 2; ++kk) {
      bf16x8 av[4], bv[4];
#pragma unroll
      for (int i = 0; i < 4; ++i) {
        int row = wr * 64 + i * 16 + r15;
        av[i] = *(const bf16x8*)&sA[row * 64 + (((kk * 4 + blk) ^ (row & 7)) * 8)];
      }
#pragma unroll
      for (int j = 0; j < 4; ++j) {
        int row = wc * 64 + j * 16 + r15;
        bv[j] = *(const bf16x8*)&sB[row * 64 + (((kk * 4 + blk) ^ (row & 7)) * 8)];
      }
#pragma unroll
      for (int i = 0; i < 4; ++i)
#pragma unroll
        for (int j = 0; j < 4; ++j) acc[i][j] = MFMA16(av[i], bv[j], acc[i][j]);
    }
    __syncthreads();
  }

  if constexpr (MODE == 3) {
    float* C = (float*)Cv;
#pragma unroll
    for (int i = 0; i < 4; ++i)
#pragma unroll
      for (int r = 0; r < 4; ++r)
#pragma unroll
        for (int j = 0; j < 4; ++j) {
          int rowl = wr * 64 + i * 16 + blk * 4 + r;   // C layout: row=(lane>>4)*4+reg
          int coll = wc * 64 + j * 16 + r15;           //           col=lane&15
          C[(size_t)(m0 + rowl) * 2048 + n0 + coll] = acc[i][j][r];
        }
    return;
  } else {
    if constexpr (MODE == 1 || MODE == 2) {
      // per-row stats over the 128 cols (= head_dim) of this tile
#pragma unroll
      for (int i = 0; i < 4; ++i)
#pragma unroll
        for (int r = 0; r < 4; ++r) {
          float sm = 0.f, sq = 0.f;
#pragma unroll
          for (int j = 0; j < 4; ++j) { float v = acc[i][j][r]; sm += v; sq += v * v; }
          sm += __shfl_xor(sm, 1); sq += __shfl_xor(sq, 1);
          sm += __shfl_xor(sm, 2); sq += __shfl_xor(sq, 2);
          sm += __shfl_xor(sm, 4); sq += __shfl_xor(sq, 4);
          sm += __shfl_xor(sm, 8); sq += __shfl_xor(sq, 8);
          if (r15 == 0) {
            int rowl = wr * 64 + i * 16 + blk * 4 + r;
            sSum[wc][rowl] = sm; sSq[wc][rowl] = sq;
          }
        }
      __syncthreads();
    }
    unsigned short* Hout = (unsigned short*)Cv;
    int h = blockIdx.x;  // BN=128 == D: one head per n-block
#pragma unroll
    for (int i = 0; i < 4; ++i)
#pragma unroll
      for (int r = 0; r < 4; ++r) {
        int rowl = wr * 64 + i * 16 + blk * 4 + r;
        float mean = 0.f, rstd = 1.f;
        if constexpr (MODE == 1 || MODE == 2) {
          float sm = sSum[0][rowl] + sSum[1][rowl];
          float sq = sSq[0][rowl] + sSq[1][rowl];
          mean = sm * 0.0078125f;
          float var = sq * 0.0078125f - mean * mean;
          rstd = rsqrtf(var + 1e-6f);
        }
        int rowg = m0 + rowl;
        int b = rowg >> 11, s = rowg & 2047;
        unsigned short* orow = Hout + (((size_t)b * 16 + h) * 2048 + s) * 128;
#pragma unroll
        for (int j = 0; j < 4; ++j) {
          int d = wc * 64 + j * 16 + r15;
          float v = acc[i][j][r];
          // log2e folded in: attention softmax runs in exp2 domain
          if constexpr (MODE == 1)
            v = (v - mean) * rstd * lnsc[d] * (0.08838834764831845f * 1.4426950408889634f);
          if constexpr (MODE == 2) v = (v - mean) * rstd * lnsc[d];
          orow[d] = f2bf(v);
        }
      }
  }
}

// ---------------- attn softmax helper (one 16-q-row group) -----------------
__device__ __forceinline__ void softmax_grp(const f32x4 (&st)[4], unsigned mw0, unsigned mw1,
                                            int blk, float& mv, float& ls,
                                            f32x4 (&o)[8], bf16x8& plo, bf16x8& phi) {
  unsigned mws0 = mw0 >> (blk * 8);
  unsigned mws1 = mw1 >> (blk * 8);
  float pvv[16];
#pragma unroll
  for (int t = 0; t < 16; ++t) {
    int s = t >> 2, r = t & 3;
    unsigned mws = (s & 2) ? mws1 : mws0;
    int bit = 4 * (s & 1) + r;  // compile-time per t
    pvv[t] = ((mws >> bit) & 1u) ? st[s][r] : -1e30f;
  }
  float c0 = max3f(pvv[0], pvv[1], pvv[2]);
  float c1 = max3f(pvv[3], pvv[4], pvv[5]);
  float c2 = max3f(pvv[6], pvv[7], pvv[8]);
  float c3 = max3f(pvv[9], pvv[10], pvv[11]);
  float c4 = max3f(pvv[12], pvv[13], pvv[14]);
  float cmax = fmaxf(max3f(c0, c1, c2), max3f(c3, c4, pvv[15]));
  cmax = fmaxf(cmax, __shfl_xor(cmax, 16));
  cmax = fmaxf(cmax, __shfl_xor(cmax, 32));
  if (!__all(cmax - mv <= 11.5f)) {  // defer-max: P bounded by 2^11.5
    float mnew = fmaxf(mv, cmax);
    float fac = exp2a(mv - mnew);
    ls *= fac;
    float fr0 = __shfl(fac, blk * 4 + 0);
    float fr1 = __shfl(fac, blk * 4 + 1);
    float fr2 = __shfl(fac, blk * 4 + 2);
    float fr3 = __shfl(fac, blk * 4 + 3);
#pragma unroll
    for (int t8 = 0; t8 < 8; ++t8) {
      o[t8][0] *= fr0; o[t8][1] *= fr1; o[t8][2] *= fr2; o[t8][3] *= fr3;
    }
    mv = mnew;
  }
#pragma unroll
  for (int t = 0; t < 16; ++t) pvv[t] = exp2a(pvv[t] - mv);
  float s0 = (pvv[0] + pvv[1]) + (pvv[2] + pvv[3]);
  float s1 = (pvv[4] + pvv[5]) + (pvv[6] + pvv[7]);
  float s2 = (pvv[8] + pvv[9]) + (pvv[10] + pvv[11]);
  float s3 = (pvv[12] + pvv[13]) + (pvv[14] + pvv[15]);
  ls += (s0 + s1) + (s2 + s3);
  uint4v w0, w1;
#pragma unroll
  for (int j = 0; j < 4; ++j) {
    w0[j] = pkbf(pvv[2 * j], pvv[2 * j + 1]);
    w1[j] = pkbf(pvv[8 + 2 * j], pvv[9 + 2 * j]);
  }
  plo = __builtin_bit_cast(bf16x8, w0);  // keys  8*blk + j
  phi = __builtin_bit_cast(bf16x8, w1);  // keys 32 + 8*blk + j
}

// ---------------- flash attention v4: QBLK=128, dbuf 2-phase staging -------
// Per wave: 2 q-groups of 16 rows; K/V frags read once, used for both groups
// (halves LDS-read per unit work). Stage(t+1) issued before compute(t), one
// __syncthreads per iter (T3-minimum 2-phase).
__global__ __launch_bounds__(256, 2) void k_attn(const unsigned short* __restrict__ Qh,
                                                 const unsigned short* __restrict__ Kh,
                                                 const unsigned short* __restrict__ Vt,
                                                 const unsigned* __restrict__ maskb,
                                                 unsigned short* __restrict__ O) {
  __shared__ __attribute__((aligned(16))) char smem[65536];  // 2 x (sK 16K + sV 16K)
  int tid = threadIdx.x, w = tid >> 6;
  int lane = tid & 63;
  int r15 = lane & 15, blk = lane >> 4;
  int bh = blockIdx.y, b = bh >> 4, h = bh & 15;
  int qb = blockIdx.x * 128;
  size_t base = (size_t)bh * (2048 * 128);
  int qrow0 = qb + w * 32 + r15;
  int qrow1 = qrow0 + 16;

  bf16x8 qf0[4], qf1[4];  // Q rows hoisted (B-operand), d = kk*32 + blk*8 + j
  {
    const unsigned short* qp0 = Qh + base + (size_t)qrow0 * 128 + blk * 8;
    const unsigned short* qp1 = Qh + base + (size_t)qrow1 * 128 + blk * 8;
#pragma unroll
    for (int kk = 0; kk < 4; ++kk) {
      qf0[kk] = *(const bf16x8*)(qp0 + kk * 32);
      qf1[kk] = *(const bf16x8*)(qp1 + kk * 32);
    }
  }
  const unsigned* mrow0 = maskb + ((size_t)b * 2048 + qrow0) * 64;
  const unsigned* mrow1 = maskb + ((size_t)b * 2048 + qrow1) * 64;

  // staging global bases (kc=0 form)
  const unsigned short* kgp[4];
  const unsigned short* vgp[4];
#pragma unroll
  for (int i = 0; i < 4; ++i) {
    int c = i * 256 + tid;
    int krow = c >> 4, kcc = c & 15;
    int key = 32 * (krow >> 5) + 8 * ((krow >> 2) & 3) + 4 * ((krow >> 4) & 1) + (krow & 3);
    kgp[i] = Kh + base + (size_t)key * 128 + ((kcc ^ (krow & 7)) * 8);
    int d = c >> 3, c8 = c & 7;
    vgp[i] = Vt + base + (size_t)d * 2048 + ((c8 ^ (d & 7)) * 8);
  }

  f32x4 o0[8] = {}, o1[8] = {};
  float m0v = -1e30f, l0 = 0.f, m1v = -1e30f, l1 = 0.f;

  // prologue: stage tile 0 into buf 0
#pragma unroll
  for (int i = 0; i < 4; ++i) {
    int c = i * 256 + tid;
    gload_lds16(kgp[i], (unsigned short*)smem + c * 8);
    gload_lds16(vgp[i], (unsigned short*)(smem + 16384) + c * 8);
  }
  __syncthreads();

  int cur = 0;
  for (int kc = 0; kc < 2048; kc += 64) {
    if (kc + 64 < 2048) {  // stage next tile into the other buffer
      char* nb = smem + ((cur ^ 1) << 15);
#pragma unroll
      for (int i = 0; i < 4; ++i) {
        int c = i * 256 + tid;
        gload_lds16(kgp[i] + (size_t)(kc + 64) * 128, (unsigned short*)nb + c * 8);
        gload_lds16(vgp[i] + (kc + 64), (unsigned short*)(nb + 16384) + c * 8);
      }
    }
    const unsigned short* sK = (const unsigned short*)(smem + (cur << 15));
    const unsigned short* sV = (const unsigned short*)(smem + (cur << 15) + 16384);

    // S^T = K . Q^T for both q-groups; kf read once, used twice
    f32x4 st0[4] = {}, st1[4] = {};
#pragma unroll
    for (int kk = 0; kk < 4; ++kk) {
      int cc = (4 * kk + blk) ^ (r15 & 7);
#pragma unroll
      for (int s = 0; s < 4; ++s) {
        bf16x8 kf = *(const bf16x8*)&sK[(16 * s + r15) * 128 + cc * 8];
        st0[s] = MFMA16(kf, qf0[kk], st0[s]);
        st1[s] = MFMA16(kf, qf1[kk], st1[s]);
      }
    }

    unsigned a0 = mrow0[kc >> 5], a1 = mrow0[(kc >> 5) + 1];
    unsigned b0 = mrow1[kc >> 5], b1 = mrow1[(kc >> 5) + 1];
    bf16x8 pf00, pf01, pf10, pf11;
    softmax_grp(st0, a0, a1, blk, m0v, l0, o0, pf00, pf01);
    softmax_grp(st1, b0, b1, blk, m1v, l1, o1, pf10, pf11);

    // PV: v-frags read once, used for both groups
#pragma unroll
    for (int t8 = 0; t8 < 8; ++t8) {
      int vr = t8 * 16 + r15;
      bf16x8 v0 = *(const bf16x8*)&sV[vr * 64 + ((blk ^ (r15 & 7)) * 8)];
      bf16x8 v1 = *(const bf16x8*)&sV[vr * 64 + (((4 + blk) ^ (r15 & 7)) * 8)];
      o0[t8] = MFMA16(pf00, v0, o0[t8]);
      o0[t8] = MFMA16(pf01, v1, o0[t8]);
      o1[t8] = MFMA16(pf10, v0, o1[t8]);
      o1[t8] = MFMA16(pf11, v1, o1[t8]);
    }
    __syncthreads();
    cur ^= 1;
  }

  // epilogue: two passes (one per q-group) through sO overlay
  float* sO = (float*)smem;
  {
    l0 += __shfl_xor(l0, 16); l0 += __shfl_xor(l0, 32);
    float inv = 1.f / l0;
    float ir0 = __shfl(inv, blk * 4 + 0), ir1 = __shfl(inv, blk * 4 + 1);
    float ir2 = __shfl(inv, blk * 4 + 2), ir3 = __shfl(inv, blk * 4 + 3);
#pragma unroll
    for (int t8 = 0; t8 < 8; ++t8) {
      int bi = (w * 16 + blk * 4) * 132 + t8 * 16 + r15;
      sO[bi] = o0[t8][0] * ir0;
      sO[bi + 132] = o0[t8][1] * ir1;
      sO[bi + 264] = o0[t8][2] * ir2;
      sO[bi + 396] = o0[t8][3] * ir3;
    }
  }
  __syncthreads();
  {
    int row = tid >> 2, d0 = (tid & 3) * 32;
    int grow = qb + (row >> 4) * 32 + (row & 15);
    unsigned short* op = O + (size_t)(b * 2048 + grow) * 2048 + h * 128 + d0;
#pragma unroll
    for (int g4 = 0; g4 < 4; ++g4) {
      ushort8 pk;
#pragma unroll
      for (int e = 0; e < 8; ++e) pk[e] = f2bf(sO[row * 132 + d0 + g4 * 8 + e]);
      *(ushort8*)(op + g4 * 8) = pk;
    }
  }
  __syncthreads();
  {
    l1 += __shfl_xor(l1, 16); l1 += __shfl_xor(l1, 32);
    float inv = 1.f / l1;
    float ir0 = __shfl(inv, blk * 4 + 0), ir1 = __shfl(inv, blk * 4 + 1);
    float ir2 = __shfl(inv, blk * 4 + 2), ir3 = __shfl(inv, blk * 4 + 3);
#pragma unroll
    for (int t8 = 0; t8 < 8; ++t8) {
      int bi = (w * 16 + blk * 4) * 132 + t8 * 16 + r15;
      sO[bi] = o1[t8][0] * ir0;
      sO[bi + 132] = o1[t8][1] * ir1;
      sO[bi + 264] = o1[t8][2] * ir2;
      sO[bi + 396] = o1[t8][3] * ir3;
    }
  }
  __syncthreads();
  {
    int row = tid >> 2, d0 = (tid & 3) * 32;
    int grow = qb + (row >> 4) * 32 + 16 + (row & 15);
    unsigned short* op = O + (size_t)(b * 2048 + grow) * 2048 + h * 128 + d0;
#pragma unroll
    for (int g4 = 0; g4 < 4; ++g4) {
      ushort8 pk;
#pragma unroll
      for (int e = 0; e < 8; ++e) pk[e] = f2bf(sO[row * 132 + d0 + g4 * 8 + e]);
      *(ushort8*)(op + g4 * 8) = pk;
    }
  }
}

// ---------------------------------------------------------------------------
extern "C" void kernel_launch(void* const* d_in, const int* in_sizes, int n_in,
                              void* d_out, int out_size, void* d_ws, size_t ws_size,
                              hipStream_t stream) {
  const float* q      = (const float*)d_in[0];
  const float* kv     = (const float*)d_in[1];
  const float* q_pos  = (const float*)d_in[2];
  const float* kv_pos = (const float*)d_in[3];
  const int*   mask   = (const int*)d_in[4];
  const float* wq     = (const float*)d_in[5];
  const float* wk     = (const float*)d_in[6];
  const float* wv     = (const float*)d_in[7];
  const float* qls    = (const float*)d_in[8];
  const float* kls    = (const float*)d_in[9];
  const float* wo     = (const float*)d_in[10];

  char* ws = (char*)d_ws;
  const size_t SZ_ACT = (size_t)4096 * 2048 * 2;  // 16 MiB
  const size_t SZ_W   = (size_t)2048 * 2048 * 2;  // 8 MiB
  unsigned short* a_q = (unsigned short*)(ws);
  unsigned short* a_k = (unsigned short*)(ws + SZ_ACT);
  unsigned short* a_v = (unsigned short*)(ws + 2 * SZ_ACT);
  unsigned short* Qh  = (unsigned short*)(ws + 3 * SZ_ACT);
  unsigned short* Kh  = (unsigned short*)(ws + 4 * SZ_ACT);
  unsigned short* Vh  = (unsigned short*)(ws + 5 * SZ_ACT);
  unsigned short* wqt = (unsigned short*)(ws + 6 * SZ_ACT);
  unsigned short* wkt = (unsigned short*)(ws + 6 * SZ_ACT + SZ_W);
  unsigned short* wvt = (unsigned short*)(ws + 6 * SZ_ACT + 2 * SZ_W);
  unsigned short* wot = (unsigned short*)(ws + 6 * SZ_ACT + 3 * SZ_W);
  unsigned*       mkb = (unsigned*)(ws + 6 * SZ_ACT + 4 * SZ_W);
  unsigned short* Ob  = a_q;  // a_q dead after Q-projection; reuse for attn out
  unsigned short* Vtr = a_k;  // a_k dead after K-projection; reuse for V^T

  const size_t NEED = 6 * SZ_ACT + 4 * SZ_W + (size_t)2 * 2048 * 64 * 4;
  if (ws_size < NEED) return;  // leave d_out poisoned -> visible failure

  k_cvt<<<8192, 256, 0, stream>>>((const float4v*)q, (const float4v*)q_pos, (ushort4v*)a_q, 2097152);
  k_cvt2<<<8192, 256, 0, stream>>>((const float4v*)kv, (const float4v*)kv_pos,
                                   (ushort4v*)a_k, (ushort4v*)a_v, 2097152);
  k_tr<<<dim3(64, 64, 4), 256, 0, stream>>>(wq, wk, wv, wo, wqt, wkt, wvt, wot);
  k_mask<<<32768, 256, 0, stream>>>(mask, (unsigned long long*)mkb);

  k_gemm<1><<<dim3(16, 32), 256, 0, stream>>>(a_q, wqt, Qh, qls);
  k_gemm<2><<<dim3(16, 32), 256, 0, stream>>>(a_k, wkt, Kh, kls);
  k_gemm<0><<<dim3(16, 32), 256, 0, stream>>>(a_v, wvt, Vh, nullptr);

  k_trv<<<dim3(32, 2, 32), 256, 0, stream>>>(Vh, Vtr);

  k_attn<<<dim3(16, 32), 256, 0, stream>>>(Qh, Kh, Vtr, mkb, Ob);

  k_gemm<3><<<dim3(16, 32), 256, 0, stream>>>(Ob, wot, d_out, nullptr);
}